// Round 9
// baseline (3272.488 us; speedup 1.0000x reference)
//
#include <hip/hip_runtime.h>
#include <hip/hip_bf16.h>

#define BATCH 4096
#define KD    2048
#define HD    2048

typedef float f32x4 __attribute__((ext_vector_type(4)));
typedef short bf16x8 __attribute__((ext_vector_type(8)));

__device__ __forceinline__ unsigned short f2bf(float f) {
  unsigned int u = __builtin_bit_cast(unsigned int, f);
  u = (u + 0x7fffu + ((u >> 16) & 1u)) >> 16;   // RNE (inputs bounded, no NaN)
  return (unsigned short)u;
}

__device__ __forceinline__ float fsigmoid(float x) { return 1.0f / (1.0f + __expf(-x)); }
__device__ __forceinline__ float ftanh(float x) {
  return 1.0f - 2.0f / (__expf(2.0f * x) + 1.0f);
}

__device__ __forceinline__ void gload16(const void* g, void* l) {
  __builtin_amdgcn_global_load_lds(
      (const __attribute__((address_space(1))) unsigned int*)(uintptr_t)g,
      (__attribute__((address_space(3))) unsigned int*)(uintptr_t)l, 16, 0, 0);
}

// ---------------- ws layout (fragment-ordered panels, 16KB, BK=64) ----------------
// Panel = [128 rows][64 k] bf16 for A (r=batch row) and W (r=n column).
// Split into two 8KB halves h = k>>5 (the two kk MFMA phases).
// Within a half, 16B chunk (r, j) (j = (k>>3)&3, k-local) lives at byte:
//   h*8192 + ((r>>6)&1)*4096 + ((r>>4)&3)*1024 + j*256 + (r&15)*16
// => every MFMA fragment read is base + lane*16 (conflict-free, zero addr math),
//    and global_load_lds staging of a half is fully contiguous.
// A panels (inputs at 0, state at OFF_STATE): panel(rb,kb) = rb*32 + kb.
// W at OFF_W: w in {0:th_u,1:et_u,2:th_w,3:et_w,4:wx}; panel = w*512 + nb*32 + kb.
#define WS_NEED   75497472ull
#define OFF_STATE (16ull << 20)
#define OFF_W     (32ull << 20)

// ---------- conversion: activations (LDS transpose to fragment order) ----------
__global__ __launch_bounds__(256) void act_convert(
    const float* __restrict__ inputs, const float* __restrict__ state,
    char* __restrict__ dst) {
  __shared__ unsigned short tile[128][72];   // 72 = 64 + 8 pad (16B-aligned rows)
  int b = blockIdx.x;                        // 0..2047, one panel per block
  const float* src = inputs;
  char* d = dst;
  int p = b;
  if (b >= 1024) { src = state; d = dst + OFF_STATE; p = b - 1024; }
  const int kb = p & 31, rb = p >> 5;
  const int tid = threadIdx.x;
#pragma unroll
  for (int i = 0; i < 8; ++i) {
    const int idx = i * 256 + tid;           // 2048 float4 units (128r x 16)
    const int r = idx >> 4, k4 = (idx & 15) * 4;
    const float4 v = *reinterpret_cast<const float4*>(
        src + (size_t)(rb * 128 + r) * KD + kb * 64 + k4);
    tile[r][k4 + 0] = f2bf(v.x); tile[r][k4 + 1] = f2bf(v.y);
    tile[r][k4 + 2] = f2bf(v.z); tile[r][k4 + 3] = f2bf(v.w);
  }
  __syncthreads();
  char* dp = d + ((size_t)p << 14);
#pragma unroll
  for (int i = 0; i < 4; ++i) {
    const int cid = i * 256 + tid;           // 1024 chunks of 16B
    const int rem = cid & 511;
    const int r = (rem >> 8) * 64 + ((rem >> 6) & 3) * 16 + (rem & 15);
    const int k0 = (cid >> 9) * 32 + ((rem >> 4) & 3) * 8;
    *reinterpret_cast<uint4*>(dp + cid * 16) =
        *reinterpret_cast<const uint4*>(&tile[r][k0]);
  }
}

// ---------- conversion: weights (transpose [k][n] -> fragment-ordered panel) ----------
__global__ __launch_bounds__(256) void weight_convert(
    const float* __restrict__ tu, const float* __restrict__ eu,
    const float* __restrict__ tw, const float* __restrict__ ew,
    const float* __restrict__ xw, char* __restrict__ dst) {
  __shared__ float tile[64][129];
  const int tid = threadIdx.x;
  const int b = blockIdx.x;                 // 0..2559
  const int w = b >> 9, panel = b & 511;
  const int nb = panel >> 5, kb = panel & 31;
  const float* W = (w == 0) ? tu : (w == 1) ? eu : (w == 2) ? tw : (w == 3) ? ew : xw;
#pragma unroll
  for (int i = 0; i < 8; ++i) {
    const int idx = i * 256 + tid;
    const int row = idx >> 5, c4 = idx & 31;
    const float4 v = *reinterpret_cast<const float4*>(
        W + (size_t)(kb * 64 + row) * HD + nb * 128 + c4 * 4);
    tile[row][c4 * 4 + 0] = v.x; tile[row][c4 * 4 + 1] = v.y;
    tile[row][c4 * 4 + 2] = v.z; tile[row][c4 * 4 + 3] = v.w;
  }
  __syncthreads();
  char* dp = dst + OFF_W + ((size_t)(w * 512 + panel) << 14);
#pragma unroll
  for (int i = 0; i < 4; ++i) {
    const int cid = i * 256 + tid;
    const int rem = cid & 511;
    const int n = (rem >> 8) * 64 + ((rem >> 6) & 3) * 16 + (rem & 15);
    const int k0 = (cid >> 9) * 32 + ((rem >> 4) & 3) * 8;
    uint4 ww;
    ww.x = (unsigned)f2bf(tile[k0 + 0][n]) | ((unsigned)f2bf(tile[k0 + 1][n]) << 16);
    ww.y = (unsigned)f2bf(tile[k0 + 2][n]) | ((unsigned)f2bf(tile[k0 + 3][n]) << 16);
    ww.z = (unsigned)f2bf(tile[k0 + 4][n]) | ((unsigned)f2bf(tile[k0 + 5][n]) << 16);
    ww.w = (unsigned)f2bf(tile[k0 + 6][n]) | ((unsigned)f2bf(tile[k0 + 7][n]) << 16);
    *reinterpret_cast<uint4*>(dp + cid * 16) = ww;
  }
}

// ---------- fused main: half-tile double-buffered pipeline, __syncthreads only ----------
// 2 x 32KB buffers: [A-half 8K][B0-half 8K][B1-half 8K][B2-half 8K] = 64KB total.
__global__ __launch_bounds__(256, 2) void cfn_main(
    const char* __restrict__ ws, const float* __restrict__ state,
    const float* __restrict__ th_b, const float* __restrict__ et_b,
    float* __restrict__ out) {
  __shared__ char sm[65536];
  const int tid = threadIdx.x;
  // bx-per-XCD swizzle (R7): each XCD owns bx pair {2x,2x+1} -> B set L2-resident.
  const int orig = blockIdx.x;
  const int xcd = orig & 7, idx = orig >> 3;     // 512 blocks: idx in [0,64)
  const int bx = xcd * 2 + (idx & 1);            // [0,16)
  const int by = idx >> 1;                       // [0,32)
  const int lane = tid & 63, wv = tid >> 6;
  const int wr = wv >> 1, wc = wv & 1;
  const int lr = lane & 15, lg = lane >> 4;
  const int t16 = tid * 16;

  const char* pAx = ws;
  const char* pAs = ws + OFF_STATE;
  const char* pW  = ws + OFF_W;

  f32x4 at[4][4], ae[4][4], ax[4][4];
#pragma unroll
  for (int m = 0; m < 4; ++m)
#pragma unroll
    for (int n = 0; n < 4; ++n)
#pragma unroll
      for (int v = 0; v < 4; ++v) { at[m][n][v] = 0.f; ae[m][n][v] = 0.f; ax[m][n][v] = 0.f; }

  // stage half-tile s (s in [0,128)): t = s>>1, h = s&1
  auto stage = [&](int s, char* dstb) {
    const int t = s >> 1, h = s & 1;
    const int kb = t & 31;
    const size_t hoff = (size_t)h * 8192;
    const char* pA = (t < 32) ? pAs : pAx;
    const char* ga = pA + ((size_t)(by * 32 + kb) << 14) + hoff;
    gload16(ga + t16, dstb + t16);
    gload16(ga + t16 + 4096, dstb + t16 + 4096);
    const int w0 = (t < 32) ? 0 : 2;
    const int nB = (t < 32) ? 2 : 3;
#pragma unroll
    for (int q = 0; q < 3; ++q) {
      if (q < nB) {
        const char* gb = pW + ((size_t)((w0 + q) * 512 + bx * 32 + kb) << 14) + hoff;
        gload16(gb + t16, dstb + 8192 + q * 8192 + t16);
        gload16(gb + t16 + 4096, dstb + 8192 + q * 8192 + t16 + 4096);
      }
    }
  };

  // compute one staged half: fragment reads are base + m(or n)*1024, conflict-free
  auto phase2 = [&](const char* buf) {
    const char* pa = buf + wr * 4096 + lg * 256 + lr * 16;
    const char* pb = buf + 8192 + wc * 4096 + lg * 256 + lr * 16;
    bf16x8 a[4], b[4];
#pragma unroll
    for (int m = 0; m < 4; ++m)
      a[m] = *reinterpret_cast<const bf16x8*>(pa + m * 1024);
#pragma unroll
    for (int n = 0; n < 4; ++n)
      b[n] = *reinterpret_cast<const bf16x8*>(pb + n * 1024);
#pragma unroll
    for (int m = 0; m < 4; ++m)
#pragma unroll
      for (int n = 0; n < 4; ++n)
        at[m][n] = __builtin_amdgcn_mfma_f32_16x16x32_bf16(a[m], b[n], at[m][n], 0, 0, 0);
#pragma unroll
    for (int n = 0; n < 4; ++n)
      b[n] = *reinterpret_cast<const bf16x8*>(pb + 8192 + n * 1024);
#pragma unroll
    for (int m = 0; m < 4; ++m)
#pragma unroll
      for (int n = 0; n < 4; ++n)
        ae[m][n] = __builtin_amdgcn_mfma_f32_16x16x32_bf16(a[m], b[n], ae[m][n], 0, 0, 0);
  };
  auto phase3 = [&](const char* buf) {
    const char* pa = buf + wr * 4096 + lg * 256 + lr * 16;
    const char* pb = buf + 8192 + wc * 4096 + lg * 256 + lr * 16;
    bf16x8 a[4], b[4];
#pragma unroll
    for (int m = 0; m < 4; ++m)
      a[m] = *reinterpret_cast<const bf16x8*>(pa + m * 1024);
#pragma unroll
    for (int n = 0; n < 4; ++n)
      b[n] = *reinterpret_cast<const bf16x8*>(pb + n * 1024);
#pragma unroll
    for (int m = 0; m < 4; ++m)
#pragma unroll
      for (int n = 0; n < 4; ++n)
        at[m][n] = __builtin_amdgcn_mfma_f32_16x16x32_bf16(a[m], b[n], at[m][n], 0, 0, 0);
#pragma unroll
    for (int n = 0; n < 4; ++n)
      b[n] = *reinterpret_cast<const bf16x8*>(pb + 8192 + n * 1024);
#pragma unroll
    for (int m = 0; m < 4; ++m)
#pragma unroll
      for (int n = 0; n < 4; ++n)
        ae[m][n] = __builtin_amdgcn_mfma_f32_16x16x32_bf16(a[m], b[n], ae[m][n], 0, 0, 0);
#pragma unroll
    for (int n = 0; n < 4; ++n)
      b[n] = *reinterpret_cast<const bf16x8*>(pb + 16384 + n * 1024);
#pragma unroll
    for (int m = 0; m < 4; ++m)
#pragma unroll
      for (int n = 0; n < 4; ++n)
        ax[m][n] = __builtin_amdgcn_mfma_f32_16x16x32_bf16(a[m], b[n], ax[m][n], 0, 0, 0);
  };

  stage(0, sm);
  __syncthreads();
  for (int s = 0; s < 128; ++s) {
    char* cur = sm + (size_t)(s & 1) * 32768;
    char* nxt = sm + (size_t)((s + 1) & 1) * 32768;
    if (s < 127) stage(s + 1, nxt);   // loads fly over compute of s
    if (s < 64) phase2(cur); else phase3(cur);
    __syncthreads();                   // waits staging of s+1; buffer swap safe
  }

  // ---- epilogue (nontemporal stores) ----
  float* const out2 = out + (size_t)BATCH * HD;
  const int n0 = bx * 128, m0 = by * 128;
#pragma unroll
  for (int n = 0; n < 4; ++n) {
    const int c = n0 + wc * 64 + n * 16 + lr;
    const float tb = th_b[c], eb = et_b[c];
#pragma unroll
    for (int m = 0; m < 4; ++m) {
#pragma unroll
      for (int v = 0; v < 4; ++v) {
        const int r = m0 + wr * 64 + m * 16 + lg * 4 + v;
        const float st = state[(size_t)r * HD + c];
        const float h = fsigmoid(at[m][n][v] + tb) * ftanh(st)
                      + fsigmoid(ae[m][n][v] + eb) * ftanh(ax[m][n][v]);
        __builtin_nontemporal_store(h, &out[(size_t)r * HD + c]);
        __builtin_nontemporal_store(h, &out2[(size_t)r * HD + c]);
      }
    }
  }
}

// ---------------- fallback if ws too small ----------------
__global__ __launch_bounds__(256, 2) void cfn_fallback(
    const float* __restrict__ inputs, const float* __restrict__ state,
    const float* __restrict__ th_u, const float* __restrict__ th_w,
    const float* __restrict__ th_b, const float* __restrict__ et_u,
    const float* __restrict__ et_w, const float* __restrict__ et_b,
    const float* __restrict__ wx_w, float* __restrict__ out) {
  __shared__ unsigned short sA[128 * 64];
  __shared__ unsigned short sB[128 * 64];
  char* const sAb = (char*)sA;
  char* const sBb = (char*)sB;
  const int tid = threadIdx.x;
  const int n0 = blockIdx.x * 128;
  const int m0 = blockIdx.y * 128;
  const int lane = tid & 63, wv = tid >> 6;
  const int wr = wv >> 1, wc = wv & 1;
  const int lr = lane & 15, lg = lane >> 4;
  const int a_kq = tid & 15, a_mb = tid >> 4;
  const int b_n = tid & 127, b_k8 = (tid >> 7) * 8;
  f32x4 acc[4][4], r2[4][4];
  auto zero_acc = [&]() {
#pragma unroll
    for (int m = 0; m < 4; ++m)
#pragma unroll
      for (int n = 0; n < 4; ++n) {
        acc[m][n][0] = 0.f; acc[m][n][1] = 0.f; acc[m][n][2] = 0.f; acc[m][n][3] = 0.f;
      }
  };
  auto gemm_seg = [&](const float* __restrict__ Ap, const float* __restrict__ Wp) {
    for (int k0 = 0; k0 < KD; k0 += 64) {
#pragma unroll
      for (int p = 0; p < 8; ++p) {
        const int m = p * 16 + a_mb;
        const float4 v = *reinterpret_cast<const float4*>(
            Ap + (size_t)(m0 + m) * KD + k0 + a_kq * 4);
        uint2 w;
        w.x = (unsigned)f2bf(v.x) | ((unsigned)f2bf(v.y) << 16);
        w.y = (unsigned)f2bf(v.z) | ((unsigned)f2bf(v.w) << 16);
        const int byte = m * 128 + ((a_kq * 8) ^ ((m & 7) << 4));
        *reinterpret_cast<uint2*>(sAb + byte) = w;
      }
#pragma unroll
      for (int p = 0; p < 4; ++p) {
        const int kb = p * 16 + b_k8;
        const float* bp = Wp + (size_t)(k0 + kb) * HD + n0 + b_n;
        uint4 w;
        w.x = (unsigned)f2bf(bp[0 * HD]) | ((unsigned)f2bf(bp[1 * HD]) << 16);
        w.y = (unsigned)f2bf(bp[2 * HD]) | ((unsigned)f2bf(bp[3 * HD]) << 16);
        w.z = (unsigned)f2bf(bp[4 * HD]) | ((unsigned)f2bf(bp[5 * HD]) << 16);
        w.w = (unsigned)f2bf(bp[6 * HD]) | ((unsigned)f2bf(bp[7 * HD]) << 16);
        const int byte = b_n * 128 + ((kb * 2) ^ ((b_n & 7) << 4));
        *reinterpret_cast<uint4*>(sBb + byte) = w;
      }
      __syncthreads();
#pragma unroll
      for (int kk = 0; kk < 2; ++kk) {
        bf16x8 af[4], bfr[4];
#pragma unroll
        for (int m = 0; m < 4; ++m) {
          const int r = wr * 64 + m * 16 + lr;
          af[m] = *reinterpret_cast<const bf16x8*>(sAb + r * 128 + ((kk * 64 + lg * 16) ^ ((r & 7) << 4)));
        }
#pragma unroll
        for (int n = 0; n < 4; ++n) {
          const int c = wc * 64 + n * 16 + lr;
          bfr[n] = *reinterpret_cast<const bf16x8*>(sBb + c * 128 + ((kk * 64 + lg * 16) ^ ((c & 7) << 4)));
        }
#pragma unroll
        for (int m = 0; m < 4; ++m)
#pragma unroll
          for (int n = 0; n < 4; ++n)
            acc[m][n] = __builtin_amdgcn_mfma_f32_16x16x32_bf16(af[m], bfr[n], acc[m][n], 0, 0, 0);
      }
      __syncthreads();
    }
  };
  zero_acc();
  gemm_seg(state, et_u);
  gemm_seg(inputs, et_w);
#pragma unroll
  for (int n = 0; n < 4; ++n) {
    const int c = n0 + wc * 64 + n * 16 + lr;
    const float eb = et_b[c];
#pragma unroll
    for (int m = 0; m < 4; ++m)
#pragma unroll
      for (int v = 0; v < 4; ++v) r2[m][n][v] = fsigmoid(acc[m][n][v] + eb);
  }
  zero_acc();
  gemm_seg(inputs, wx_w);
#pragma unroll
  for (int m = 0; m < 4; ++m)
#pragma unroll
    for (int n = 0; n < 4; ++n)
#pragma unroll
      for (int v = 0; v < 4; ++v) r2[m][n][v] *= ftanh(acc[m][n][v]);
  zero_acc();
  gemm_seg(state, th_u);
  gemm_seg(inputs, th_w);
  float* const out2 = out + (size_t)BATCH * HD;
#pragma unroll
  for (int n = 0; n < 4; ++n) {
    const int c = n0 + wc * 64 + n * 16 + lr;
    const float tb = th_b[c];
#pragma unroll
    for (int m = 0; m < 4; ++m)
#pragma unroll
      for (int v = 0; v < 4; ++v) {
        const int r = m0 + wr * 64 + m * 16 + lg * 4 + v;
        const float st = state[(size_t)r * HD + c];
        const float h = fsigmoid(acc[m][n][v] + tb) * ftanh(st) + r2[m][n][v];
        out[(size_t)r * HD + c] = h;
        out2[(size_t)r * HD + c] = h;
      }
  }
}

extern "C" void kernel_launch(void* const* d_in, const int* in_sizes, int n_in,
                              void* d_out, int out_size, void* d_ws, size_t ws_size,
                              hipStream_t stream) {
  const float* inputs = (const float*)d_in[0];
  const float* state  = (const float*)d_in[1];
  const float* th_u   = (const float*)d_in[2];
  const float* th_w   = (const float*)d_in[3];
  const float* th_b   = (const float*)d_in[4];
  const float* et_u   = (const float*)d_in[5];
  const float* et_w   = (const float*)d_in[6];
  const float* et_b   = (const float*)d_in[7];
  const float* wx_w   = (const float*)d_in[8];
  float* out = (float*)d_out;

  if (ws_size < WS_NEED) {
    dim3 grid(HD / 128, BATCH / 128);
    hipLaunchKernelGGL(cfn_fallback, grid, dim3(256), 0, stream,
                       inputs, state, th_u, th_w, th_b, et_u, et_w, et_b, wx_w, out);
    return;
  }

  char* ws = (char*)d_ws;
  hipLaunchKernelGGL(act_convert, dim3(2048), dim3(256), 0, stream, inputs, state, ws);
  hipLaunchKernelGGL(weight_convert, dim3(2560), dim3(256), 0, stream,
                     th_u, et_u, th_w, et_w, wx_w, ws);
  hipLaunchKernelGGL(cfn_main, dim3(512), dim3(256), 0, stream,
                     ws, state, th_b, et_b, out);
}

// Round 11
// 209.557 us; speedup vs baseline: 15.6162x; 15.6162x over previous
//
#include <hip/hip_runtime.h>
#include <hip/hip_bf16.h>

#define BATCH 4096
#define KD    2048
#define HD    2048

typedef float f32x4 __attribute__((ext_vector_type(4)));
typedef short bf16x8 __attribute__((ext_vector_type(8)));

__device__ __forceinline__ unsigned short f2bf(float f) {
  unsigned int u = __builtin_bit_cast(unsigned int, f);
  u = (u + 0x7fffu + ((u >> 16) & 1u)) >> 16;   // RNE (inputs bounded, no NaN)
  return (unsigned short)u;
}

__device__ __forceinline__ float fsigmoid(float x) { return 1.0f / (1.0f + __expf(-x)); }
__device__ __forceinline__ float ftanh(float x) {
  return 1.0f - 2.0f / (__expf(2.0f * x) + 1.0f);
}

__device__ __forceinline__ void gload16(const void* g, void* l) {
  __builtin_amdgcn_global_load_lds(
      (const __attribute__((address_space(1))) unsigned int*)(uintptr_t)g,
      (__attribute__((address_space(3))) unsigned int*)(uintptr_t)l, 16, 0, 0);
}

// ---------------- ws layout (round-2 proven 16KB panels, BK=64) ----------------
// A (inputs at 0, state at OFF_STATE): panel(rb,kb) = rb*32+kb, 16KB: [128 r][64 k].
// W at OFF_W: w in {0:th_u,1:et_u,2:th_w,3:et_w,4:wx}; panel = w*512 + nb*32 + kb.
// Intra-panel byte(r,k) = r*128 + ((2k) ^ ((r&7)<<4))
#define WS_NEED   75497472ull
#define OFF_STATE (16ull << 20)
#define OFF_W     (32ull << 20)

// ---------- fused conversion: one dispatch for activations + weights ----------
// blocks [0, 8192): activation chunks (R2 act_convert, nt loads)
// blocks [8192, 10752): weight panels (R2 weight_convert, nt loads)
__global__ __launch_bounds__(256) void convert_all(
    const float* __restrict__ inputs, const float* __restrict__ state,
    const float* __restrict__ tu, const float* __restrict__ eu,
    const float* __restrict__ tw, const float* __restrict__ ew,
    const float* __restrict__ xw, char* __restrict__ dst) {
  __shared__ float tile[64][129];
  const int tid = threadIdx.x;
  const int blk = blockIdx.x;

  if (blk < 8192) {
    // ---- activations: 2M chunks of 16B ----
    unsigned gid = blk * 256 + tid;
    const float* src = inputs;
    char* d = dst;
    unsigned id = gid;
    if (gid >= (1u << 20)) { src = state; d = dst + OFF_STATE; id = gid - (1u << 20); }
    const unsigned cid = id & 1023, panel = id >> 10;
    const unsigned kb = panel & 31, rb = panel >> 5;
    const unsigned x = cid * 16, r = x >> 7, xb = x & 127;
    const unsigned k0 = (xb ^ ((r & 7) << 4)) >> 1;
    const float* s = src + (size_t)(rb * 128 + r) * KD + kb * 64 + k0;
    const f32x4 v0 = __builtin_nontemporal_load(reinterpret_cast<const f32x4*>(s));
    const f32x4 v1 = __builtin_nontemporal_load(reinterpret_cast<const f32x4*>(s + 4));
    uint4 w;
    w.x = (unsigned)f2bf(v0[0]) | ((unsigned)f2bf(v0[1]) << 16);
    w.y = (unsigned)f2bf(v0[2]) | ((unsigned)f2bf(v0[3]) << 16);
    w.z = (unsigned)f2bf(v1[0]) | ((unsigned)f2bf(v1[1]) << 16);
    w.w = (unsigned)f2bf(v1[2]) | ((unsigned)f2bf(v1[3]) << 16);
    *reinterpret_cast<uint4*>(d + (size_t)id * 16) = w;
    return;
  }

  // ---- weights: LDS transpose [k][n] -> swizzled panel (row = n) ----
  const int b = blk - 8192;                 // 0..2559
  const int w = b >> 9, panel = b & 511;
  const int nb = panel >> 5, kb = panel & 31;
  const float* W = (w == 0) ? tu : (w == 1) ? eu : (w == 2) ? tw : (w == 3) ? ew : xw;
#pragma unroll
  for (int i = 0; i < 8; ++i) {
    const int idx = i * 256 + tid;
    const int row = idx >> 5, c4 = idx & 31;
    const f32x4 v = __builtin_nontemporal_load(reinterpret_cast<const f32x4*>(
        W + (size_t)(kb * 64 + row) * HD + nb * 128 + c4 * 4));
    tile[row][c4 * 4 + 0] = v[0]; tile[row][c4 * 4 + 1] = v[1];
    tile[row][c4 * 4 + 2] = v[2]; tile[row][c4 * 4 + 3] = v[3];
  }
  __syncthreads();
  char* d = dst + OFF_W + ((size_t)(w * 512 + panel) << 14);
#pragma unroll
  for (int i = 0; i < 4; ++i) {
    const int cid = i * 256 + tid;
    const int n = cid >> 3, xb = (cid & 7) * 16;
    const int k0 = (xb ^ ((n & 7) << 4)) >> 1;
    uint4 ww;
    ww.x = (unsigned)f2bf(tile[k0 + 0][n]) | ((unsigned)f2bf(tile[k0 + 1][n]) << 16);
    ww.y = (unsigned)f2bf(tile[k0 + 2][n]) | ((unsigned)f2bf(tile[k0 + 3][n]) << 16);
    ww.z = (unsigned)f2bf(tile[k0 + 4][n]) | ((unsigned)f2bf(tile[k0 + 5][n]) << 16);
    ww.w = (unsigned)f2bf(tile[k0 + 6][n]) | ((unsigned)f2bf(tile[k0 + 7][n]) << 16);
    *reinterpret_cast<uint4*>(d + n * 128 + xb) = ww;
  }
}

// ---------- fused main kernel: R7 verbatim (serial stage->sync->compute) ----------
__global__ __launch_bounds__(256, 2) void cfn_main(
    const char* __restrict__ ws, const float* __restrict__ state,
    const float* __restrict__ th_b, const float* __restrict__ et_b,
    float* __restrict__ out) {
  __shared__ char sm[65536];
  const int tid = threadIdx.x;
  // bx-per-XCD swizzle: each XCD owns bx pair {2x,2x+1} -> B set L2-resident.
  const int orig = blockIdx.x;
  const int xcd = orig & 7, idx = orig >> 3;     // 512 blocks: idx in [0,64)
  const int bx = xcd * 2 + (idx & 1);            // [0,16)
  const int by = idx >> 1;                       // [0,32)
  const int lane = tid & 63, wv = tid >> 6;
  const int wr = wv >> 1, wc = wv & 1;
  const int lr = lane & 15, lg = lane >> 4;
  const int t16 = tid * 16;

  const char* pAx = ws;
  const char* pAs = ws + OFF_STATE;
  const char* pW  = ws + OFF_W;

  f32x4 at[4][4], ae[4][4], ax[4][4];
#pragma unroll
  for (int m = 0; m < 4; ++m)
#pragma unroll
    for (int n = 0; n < 4; ++n)
#pragma unroll
      for (int v = 0; v < 4; ++v) { at[m][n][v] = 0.f; ae[m][n][v] = 0.f; ax[m][n][v] = 0.f; }

  // ---- pass 1: state @ th_u -> at ; state @ et_u -> ae ----
  for (int kb = 0; kb < 32; ++kb) {
    const char* ga = pAs + ((size_t)(by * 32 + kb) << 14);
    const char* g0 = pW + ((size_t)(0 * 512 + bx * 32 + kb) << 14);
    const char* g1 = pW + ((size_t)(1 * 512 + bx * 32 + kb) << 14);
#pragma unroll
    for (int i = 0; i < 4; ++i) {
      gload16(ga + t16 + i * 4096, sm + t16 + i * 4096);
      gload16(g0 + t16 + i * 4096, sm + 16384 + t16 + i * 4096);
      gload16(g1 + t16 + i * 4096, sm + 32768 + t16 + i * 4096);
    }
    __syncthreads();
#pragma unroll
    for (int kk = 0; kk < 2; ++kk) {
      const int kc = kk * 64 + lg * 16;
      bf16x8 a[4], b[4];
#pragma unroll
      for (int m = 0; m < 4; ++m) {
        const int r = wr * 64 + m * 16 + lr;
        a[m] = *reinterpret_cast<const bf16x8*>(sm + r * 128 + (kc ^ ((r & 7) << 4)));
      }
#pragma unroll
      for (int n = 0; n < 4; ++n) {
        const int c = wc * 64 + n * 16 + lr;
        b[n] = *reinterpret_cast<const bf16x8*>(sm + 16384 + c * 128 + (kc ^ ((c & 7) << 4)));
      }
#pragma unroll
      for (int m = 0; m < 4; ++m)
#pragma unroll
        for (int n = 0; n < 4; ++n)
          at[m][n] = __builtin_amdgcn_mfma_f32_16x16x32_bf16(a[m], b[n], at[m][n], 0, 0, 0);
#pragma unroll
      for (int n = 0; n < 4; ++n) {
        const int c = wc * 64 + n * 16 + lr;
        b[n] = *reinterpret_cast<const bf16x8*>(sm + 32768 + c * 128 + (kc ^ ((c & 7) << 4)));
      }
#pragma unroll
      for (int m = 0; m < 4; ++m)
#pragma unroll
        for (int n = 0; n < 4; ++n)
          ae[m][n] = __builtin_amdgcn_mfma_f32_16x16x32_bf16(a[m], b[n], ae[m][n], 0, 0, 0);
    }
    __syncthreads();
  }

  // ---- pass 2: inputs @ th_w -> at ; inputs @ et_w -> ae ; inputs @ wx -> ax ----
  for (int kb = 0; kb < 32; ++kb) {
    const char* ga = pAx + ((size_t)(by * 32 + kb) << 14);
    const char* g0 = pW + ((size_t)(2 * 512 + bx * 32 + kb) << 14);
    const char* g1 = pW + ((size_t)(3 * 512 + bx * 32 + kb) << 14);
    const char* g2 = pW + ((size_t)(4 * 512 + bx * 32 + kb) << 14);
#pragma unroll
    for (int i = 0; i < 4; ++i) {
      gload16(ga + t16 + i * 4096, sm + t16 + i * 4096);
      gload16(g0 + t16 + i * 4096, sm + 16384 + t16 + i * 4096);
      gload16(g1 + t16 + i * 4096, sm + 32768 + t16 + i * 4096);
      gload16(g2 + t16 + i * 4096, sm + 49152 + t16 + i * 4096);
    }
    __syncthreads();
#pragma unroll
    for (int kk = 0; kk < 2; ++kk) {
      const int kc = kk * 64 + lg * 16;
      bf16x8 a[4], b[4];
#pragma unroll
      for (int m = 0; m < 4; ++m) {
        const int r = wr * 64 + m * 16 + lr;
        a[m] = *reinterpret_cast<const bf16x8*>(sm + r * 128 + (kc ^ ((r & 7) << 4)));
      }
#pragma unroll
      for (int n = 0; n < 4; ++n) {
        const int c = wc * 64 + n * 16 + lr;
        b[n] = *reinterpret_cast<const bf16x8*>(sm + 16384 + c * 128 + (kc ^ ((c & 7) << 4)));
      }
#pragma unroll
      for (int m = 0; m < 4; ++m)
#pragma unroll
        for (int n = 0; n < 4; ++n)
          at[m][n] = __builtin_amdgcn_mfma_f32_16x16x32_bf16(a[m], b[n], at[m][n], 0, 0, 0);
#pragma unroll
      for (int n = 0; n < 4; ++n) {
        const int c = wc * 64 + n * 16 + lr;
        b[n] = *reinterpret_cast<const bf16x8*>(sm + 32768 + c * 128 + (kc ^ ((c & 7) << 4)));
      }
#pragma unroll
      for (int m = 0; m < 4; ++m)
#pragma unroll
        for (int n = 0; n < 4; ++n)
          ae[m][n] = __builtin_amdgcn_mfma_f32_16x16x32_bf16(a[m], b[n], ae[m][n], 0, 0, 0);
#pragma unroll
      for (int n = 0; n < 4; ++n) {
        const int c = wc * 64 + n * 16 + lr;
        b[n] = *reinterpret_cast<const bf16x8*>(sm + 49152 + c * 128 + (kc ^ ((c & 7) << 4)));
      }
#pragma unroll
      for (int m = 0; m < 4; ++m)
#pragma unroll
        for (int n = 0; n < 4; ++n)
          ax[m][n] = __builtin_amdgcn_mfma_f32_16x16x32_bf16(a[m], b[n], ax[m][n], 0, 0, 0);
    }
    __syncthreads();
  }

  // ---- epilogue (nontemporal stores) ----
  float* const out2 = out + (size_t)BATCH * HD;
  const int n0 = bx * 128, m0 = by * 128;
#pragma unroll
  for (int n = 0; n < 4; ++n) {
    const int c = n0 + wc * 64 + n * 16 + lr;
    const float tb = th_b[c], eb = et_b[c];
#pragma unroll
    for (int m = 0; m < 4; ++m) {
#pragma unroll
      for (int v = 0; v < 4; ++v) {
        const int r = m0 + wr * 64 + m * 16 + lg * 4 + v;
        const float st = state[(size_t)r * HD + c];
        const float h = fsigmoid(at[m][n][v] + tb) * ftanh(st)
                      + fsigmoid(ae[m][n][v] + eb) * ftanh(ax[m][n][v]);
        __builtin_nontemporal_store(h, &out[(size_t)r * HD + c]);
        __builtin_nontemporal_store(h, &out2[(size_t)r * HD + c]);
      }
    }
  }
}

// ---------------- fallback if ws too small ----------------
__global__ __launch_bounds__(256, 2) void cfn_fallback(
    const float* __restrict__ inputs, const float* __restrict__ state,
    const float* __restrict__ th_u, const float* __restrict__ th_w,
    const float* __restrict__ th_b, const float* __restrict__ et_u,
    const float* __restrict__ et_w, const float* __restrict__ et_b,
    const float* __restrict__ wx_w, float* __restrict__ out) {
  __shared__ unsigned short sA[128 * 64];
  __shared__ unsigned short sB[128 * 64];
  char* const sAb = (char*)sA;
  char* const sBb = (char*)sB;
  const int tid = threadIdx.x;
  const int n0 = blockIdx.x * 128;
  const int m0 = blockIdx.y * 128;
  const int lane = tid & 63, wv = tid >> 6;
  const int wr = wv >> 1, wc = wv & 1;
  const int lr = lane & 15, lg = lane >> 4;
  const int a_kq = tid & 15, a_mb = tid >> 4;
  const int b_n = tid & 127, b_k8 = (tid >> 7) * 8;
  f32x4 acc[4][4], r2[4][4];
  auto zero_acc = [&]() {
#pragma unroll
    for (int m = 0; m < 4; ++m)
#pragma unroll
      for (int n = 0; n < 4; ++n) {
        acc[m][n][0] = 0.f; acc[m][n][1] = 0.f; acc[m][n][2] = 0.f; acc[m][n][3] = 0.f;
      }
  };
  auto gemm_seg = [&](const float* __restrict__ Ap, const float* __restrict__ Wp) {
    for (int k0 = 0; k0 < KD; k0 += 64) {
#pragma unroll
      for (int p = 0; p < 8; ++p) {
        const int m = p * 16 + a_mb;
        const float4 v = *reinterpret_cast<const float4*>(
            Ap + (size_t)(m0 + m) * KD + k0 + a_kq * 4);
        uint2 w;
        w.x = (unsigned)f2bf(v.x) | ((unsigned)f2bf(v.y) << 16);
        w.y = (unsigned)f2bf(v.z) | ((unsigned)f2bf(v.w) << 16);
        const int byte = m * 128 + ((a_kq * 8) ^ ((m & 7) << 4));
        *reinterpret_cast<uint2*>(sAb + byte) = w;
      }
#pragma unroll
      for (int p = 0; p < 4; ++p) {
        const int kb = p * 16 + b_k8;
        const float* bp = Wp + (size_t)(k0 + kb) * HD + n0 + b_n;
        uint4 w;
        w.x = (unsigned)f2bf(bp[0 * HD]) | ((unsigned)f2bf(bp[1 * HD]) << 16);
        w.y = (unsigned)f2bf(bp[2 * HD]) | ((unsigned)f2bf(bp[3 * HD]) << 16);
        w.z = (unsigned)f2bf(bp[4 * HD]) | ((unsigned)f2bf(bp[5 * HD]) << 16);
        w.w = (unsigned)f2bf(bp[6 * HD]) | ((unsigned)f2bf(bp[7 * HD]) << 16);
        const int byte = b_n * 128 + ((kb * 2) ^ ((b_n & 7) << 4));
        *reinterpret_cast<uint4*>(sBb + byte) = w;
      }
      __syncthreads();
#pragma unroll
      for (int kk = 0; kk < 2; ++kk) {
        bf16x8 af[4], bfr[4];
#pragma unroll
        for (int m = 0; m < 4; ++m) {
          const int r = wr * 64 + m * 16 + lr;
          af[m] = *reinterpret_cast<const bf16x8*>(sAb + r * 128 + ((kk * 64 + lg * 16) ^ ((r & 7) << 4)));
        }
#pragma unroll
        for (int n = 0; n < 4; ++n) {
          const int c = wc * 64 + n * 16 + lr;
          bfr[n] = *reinterpret_cast<const bf16x8*>(sBb + c * 128 + ((kk * 64 + lg * 16) ^ ((c & 7) << 4)));
        }
#pragma unroll
        for (int m = 0; m < 4; ++m)
#pragma unroll
          for (int n = 0; n < 4; ++n)
            acc[m][n] = __builtin_amdgcn_mfma_f32_16x16x32_bf16(af[m], bfr[n], acc[m][n], 0, 0, 0);
      }
      __syncthreads();
    }
  };
  zero_acc();
  gemm_seg(state, et_u);
  gemm_seg(inputs, et_w);
#pragma unroll
  for (int n = 0; n < 4; ++n) {
    const int c = n0 + wc * 64 + n * 16 + lr;
    const float eb = et_b[c];
#pragma unroll
    for (int m = 0; m < 4; ++m)
#pragma unroll
      for (int v = 0; v < 4; ++v) r2[m][n][v] = fsigmoid(acc[m][n][v] + eb);
  }
  zero_acc();
  gemm_seg(inputs, wx_w);
#pragma unroll
  for (int m = 0; m < 4; ++m)
#pragma unroll
    for (int n = 0; n < 4; ++n)
#pragma unroll
      for (int v = 0; v < 4; ++v) r2[m][n][v] *= ftanh(acc[m][n][v]);
  zero_acc();
  gemm_seg(state, th_u);
  gemm_seg(inputs, th_w);
  float* const out2 = out + (size_t)BATCH * HD;
#pragma unroll
  for (int n = 0; n < 4; ++n) {
    const int c = n0 + wc * 64 + n * 16 + lr;
    const float tb = th_b[c];
#pragma unroll
    for (int m = 0; m < 4; ++m)
#pragma unroll
      for (int v = 0; v < 4; ++v) {
        const int r = m0 + wr * 64 + m * 16 + lg * 4 + v;
        const float st = state[(size_t)r * HD + c];
        const float h = fsigmoid(acc[m][n][v] + tb) * ftanh(st) + r2[m][n][v];
        out[(size_t)r * HD + c] = h;
        out2[(size_t)r * HD + c] = h;
      }
  }
}

extern "C" void kernel_launch(void* const* d_in, const int* in_sizes, int n_in,
                              void* d_out, int out_size, void* d_ws, size_t ws_size,
                              hipStream_t stream) {
  const float* inputs = (const float*)d_in[0];
  const float* state  = (const float*)d_in[1];
  const float* th_u   = (const float*)d_in[2];
  const float* th_w   = (const float*)d_in[3];
  const float* th_b   = (const float*)d_in[4];
  const float* et_u   = (const float*)d_in[5];
  const float* et_w   = (const float*)d_in[6];
  const float* et_b   = (const float*)d_in[7];
  const float* wx_w   = (const float*)d_in[8];
  float* out = (float*)d_out;

  if (ws_size < WS_NEED) {
    dim3 grid(HD / 128, BATCH / 128);
    hipLaunchKernelGGL(cfn_fallback, grid, dim3(256), 0, stream,
                       inputs, state, th_u, th_w, th_b, et_u, et_w, et_b, wx_w, out);
    return;
  }

  char* ws = (char*)d_ws;
  hipLaunchKernelGGL(convert_all, dim3(10752), dim3(256), 0, stream,
                     inputs, state, th_u, et_u, th_w, et_w, wx_w, ws);
  hipLaunchKernelGGL(cfn_main, dim3(512), dim3(256), 0, stream,
                     ws, state, th_b, et_b, out);
}

// Round 12
// 183.029 us; speedup vs baseline: 17.8796x; 1.1449x over previous
//
#include <hip/hip_runtime.h>
#include <hip/hip_bf16.h>

#define BATCH 4096
#define KD    2048
#define HD    2048

typedef float f32x4 __attribute__((ext_vector_type(4)));
typedef short bf16x8 __attribute__((ext_vector_type(8)));

__device__ __forceinline__ unsigned short f2bf(float f) {
  unsigned int u = __builtin_bit_cast(unsigned int, f);
  u = (u + 0x7fffu + ((u >> 16) & 1u)) >> 16;   // RNE (inputs bounded, no NaN)
  return (unsigned short)u;
}

__device__ __forceinline__ float fsigmoid(float x) { return 1.0f / (1.0f + __expf(-x)); }
__device__ __forceinline__ float ftanh(float x) {
  return 1.0f - 2.0f / (__expf(2.0f * x) + 1.0f);
}

__device__ __forceinline__ void gload16(const void* g, void* l) {
  __builtin_amdgcn_global_load_lds(
      (const __attribute__((address_space(1))) unsigned int*)(uintptr_t)g,
      (__attribute__((address_space(3))) unsigned int*)(uintptr_t)l, 16, 0, 0);
}

// ---------------- ws layout (proven 16KB panels, BK=64) ----------------
// A (inputs at 0, state at OFF_STATE): panel(rb,kb) = rb*32+kb, 16KB: [128 r][64 k].
// W at OFF_W: w in {0:th_u,1:et_u,2:th_w,3:et_w,4:wx}; panel = w*512 + nb*32 + kb.
// Intra-panel byte(r,k) = r*128 + ((2k) ^ ((r&7)<<4))
#define WS_NEED   75497472ull
#define OFF_STATE (16ull << 20)
#define OFF_W     (32ull << 20)

// ---------- conversion: activations ----------
__global__ __launch_bounds__(256) void act_convert(
    const float* __restrict__ inputs, const float* __restrict__ state,
    char* __restrict__ dst) {
  unsigned gid = blockIdx.x * 256 + threadIdx.x;   // 2M chunks of 16B
  const float* src = inputs;
  char* d = dst;
  unsigned id = gid;
  if (gid >= (1u << 20)) { src = state; d = dst + OFF_STATE; id = gid - (1u << 20); }
  const unsigned cid = id & 1023, panel = id >> 10;
  const unsigned kb = panel & 31, rb = panel >> 5;
  const unsigned x = cid * 16, r = x >> 7, xb = x & 127;
  const unsigned k0 = (xb ^ ((r & 7) << 4)) >> 1;
  const float* s = src + (size_t)(rb * 128 + r) * KD + kb * 64 + k0;
  const float4 v0 = *reinterpret_cast<const float4*>(s);
  const float4 v1 = *reinterpret_cast<const float4*>(s + 4);
  uint4 w;
  w.x = (unsigned)f2bf(v0.x) | ((unsigned)f2bf(v0.y) << 16);
  w.y = (unsigned)f2bf(v0.z) | ((unsigned)f2bf(v0.w) << 16);
  w.z = (unsigned)f2bf(v1.x) | ((unsigned)f2bf(v1.y) << 16);
  w.w = (unsigned)f2bf(v1.z) | ((unsigned)f2bf(v1.w) << 16);
  *reinterpret_cast<uint4*>(d + (size_t)id * 16) = w;
}

// ---------- conversion: weights ----------
__global__ __launch_bounds__(256) void weight_convert(
    const float* __restrict__ tu, const float* __restrict__ eu,
    const float* __restrict__ tw, const float* __restrict__ ew,
    const float* __restrict__ xw, char* __restrict__ dst) {
  __shared__ float tile[64][129];
  const int tid = threadIdx.x;
  const int b = blockIdx.x;                 // 0..2559
  const int w = b >> 9, panel = b & 511;
  const int nb = panel >> 5, kb = panel & 31;
  const float* W = (w == 0) ? tu : (w == 1) ? eu : (w == 2) ? tw : (w == 3) ? ew : xw;
#pragma unroll
  for (int i = 0; i < 8; ++i) {
    const int idx = i * 256 + tid;
    const int row = idx >> 5, c4 = idx & 31;
    const float4 v = *reinterpret_cast<const float4*>(
        W + (size_t)(kb * 64 + row) * HD + nb * 128 + c4 * 4);
    tile[row][c4 * 4 + 0] = v.x; tile[row][c4 * 4 + 1] = v.y;
    tile[row][c4 * 4 + 2] = v.z; tile[row][c4 * 4 + 3] = v.w;
  }
  __syncthreads();
  char* d = dst + OFF_W + ((size_t)(w * 512 + panel) << 14);
#pragma unroll
  for (int i = 0; i < 4; ++i) {
    const int cid = i * 256 + tid;
    const int n = cid >> 3, xb = (cid & 7) * 16;
    const int k0 = (xb ^ ((n & 7) << 4)) >> 1;
    uint4 ww;
    ww.x = (unsigned)f2bf(tile[k0 + 0][n]) | ((unsigned)f2bf(tile[k0 + 1][n]) << 16);
    ww.y = (unsigned)f2bf(tile[k0 + 2][n]) | ((unsigned)f2bf(tile[k0 + 3][n]) << 16);
    ww.z = (unsigned)f2bf(tile[k0 + 4][n]) | ((unsigned)f2bf(tile[k0 + 5][n]) << 16);
    ww.w = (unsigned)f2bf(tile[k0 + 6][n]) | ((unsigned)f2bf(tile[k0 + 7][n]) << 16);
    *reinterpret_cast<uint4*>(d + n * 128 + xb) = ww;
  }
}

// ---------- fused main kernel: serial stage->sync->compute, bx-per-XCD ----------
__global__ __launch_bounds__(256, 2) void cfn_main(
    const char* __restrict__ ws, const float* __restrict__ state,
    const float* __restrict__ th_b, const float* __restrict__ et_b,
    float* __restrict__ out) {
  __shared__ char sm[65536];
  const int tid = threadIdx.x;
  // bx-per-XCD swizzle: each XCD owns bx pair {2x,2x+1} -> B set L2-resident.
  const int orig = blockIdx.x;
  const int xcd = orig & 7, idx = orig >> 3;     // 512 blocks: idx in [0,64)
  const int bx = xcd * 2 + (idx & 1);            // [0,16)
  const int by = idx >> 1;                       // [0,32)
  const int lane = tid & 63, wv = tid >> 6;
  const int wr = wv >> 1, wc = wv & 1;
  const int lr = lane & 15, lg = lane >> 4;
  const int t16 = tid * 16;

  const char* pAx = ws;
  const char* pAs = ws + OFF_STATE;
  const char* pW  = ws + OFF_W;

  f32x4 at[4][4], ae[4][4], ax[4][4];
#pragma unroll
  for (int m = 0; m < 4; ++m)
#pragma unroll
    for (int n = 0; n < 4; ++n)
#pragma unroll
      for (int v = 0; v < 4; ++v) { at[m][n][v] = 0.f; ae[m][n][v] = 0.f; ax[m][n][v] = 0.f; }

  // ---- pass 1: state @ th_u -> at ; state @ et_u -> ae ----
  for (int kb = 0; kb < 32; ++kb) {
    const char* ga = pAs + ((size_t)(by * 32 + kb) << 14);
    const char* g0 = pW + ((size_t)(0 * 512 + bx * 32 + kb) << 14);
    const char* g1 = pW + ((size_t)(1 * 512 + bx * 32 + kb) << 14);
#pragma unroll
    for (int i = 0; i < 4; ++i) {
      gload16(ga + t16 + i * 4096, sm + t16 + i * 4096);
      gload16(g0 + t16 + i * 4096, sm + 16384 + t16 + i * 4096);
      gload16(g1 + t16 + i * 4096, sm + 32768 + t16 + i * 4096);
    }
    __syncthreads();
#pragma unroll
    for (int kk = 0; kk < 2; ++kk) {
      const int kc = kk * 64 + lg * 16;
      bf16x8 a[4], b[4];
#pragma unroll
      for (int m = 0; m < 4; ++m) {
        const int r = wr * 64 + m * 16 + lr;
        a[m] = *reinterpret_cast<const bf16x8*>(sm + r * 128 + (kc ^ ((r & 7) << 4)));
      }
#pragma unroll
      for (int n = 0; n < 4; ++n) {
        const int c = wc * 64 + n * 16 + lr;
        b[n] = *reinterpret_cast<const bf16x8*>(sm + 16384 + c * 128 + (kc ^ ((c & 7) << 4)));
      }
#pragma unroll
      for (int m = 0; m < 4; ++m)
#pragma unroll
        for (int n = 0; n < 4; ++n)
          at[m][n] = __builtin_amdgcn_mfma_f32_16x16x32_bf16(a[m], b[n], at[m][n], 0, 0, 0);
#pragma unroll
      for (int n = 0; n < 4; ++n) {
        const int c = wc * 64 + n * 16 + lr;
        b[n] = *reinterpret_cast<const bf16x8*>(sm + 32768 + c * 128 + (kc ^ ((c & 7) << 4)));
      }
#pragma unroll
      for (int m = 0; m < 4; ++m)
#pragma unroll
        for (int n = 0; n < 4; ++n)
          ae[m][n] = __builtin_amdgcn_mfma_f32_16x16x32_bf16(a[m], b[n], ae[m][n], 0, 0, 0);
    }
    __syncthreads();
  }

  // ---- pass 2: inputs @ th_w -> at ; inputs @ et_w -> ae ; inputs @ wx -> ax ----
  for (int kb = 0; kb < 32; ++kb) {
    const char* ga = pAx + ((size_t)(by * 32 + kb) << 14);
    const char* g0 = pW + ((size_t)(2 * 512 + bx * 32 + kb) << 14);
    const char* g1 = pW + ((size_t)(3 * 512 + bx * 32 + kb) << 14);
    const char* g2 = pW + ((size_t)(4 * 512 + bx * 32 + kb) << 14);
#pragma unroll
    for (int i = 0; i < 4; ++i) {
      gload16(ga + t16 + i * 4096, sm + t16 + i * 4096);
      gload16(g0 + t16 + i * 4096, sm + 16384 + t16 + i * 4096);
      gload16(g1 + t16 + i * 4096, sm + 32768 + t16 + i * 4096);
      gload16(g2 + t16 + i * 4096, sm + 49152 + t16 + i * 4096);
    }
    __syncthreads();
#pragma unroll
    for (int kk = 0; kk < 2; ++kk) {
      const int kc = kk * 64 + lg * 16;
      bf16x8 a[4], b[4];
#pragma unroll
      for (int m = 0; m < 4; ++m) {
        const int r = wr * 64 + m * 16 + lr;
        a[m] = *reinterpret_cast<const bf16x8*>(sm + r * 128 + (kc ^ ((r & 7) << 4)));
      }
#pragma unroll
      for (int n = 0; n < 4; ++n) {
        const int c = wc * 64 + n * 16 + lr;
        b[n] = *reinterpret_cast<const bf16x8*>(sm + 16384 + c * 128 + (kc ^ ((c & 7) << 4)));
      }
#pragma unroll
      for (int m = 0; m < 4; ++m)
#pragma unroll
        for (int n = 0; n < 4; ++n)
          at[m][n] = __builtin_amdgcn_mfma_f32_16x16x32_bf16(a[m], b[n], at[m][n], 0, 0, 0);
#pragma unroll
      for (int n = 0; n < 4; ++n) {
        const int c = wc * 64 + n * 16 + lr;
        b[n] = *reinterpret_cast<const bf16x8*>(sm + 32768 + c * 128 + (kc ^ ((c & 7) << 4)));
      }
#pragma unroll
      for (int m = 0; m < 4; ++m)
#pragma unroll
        for (int n = 0; n < 4; ++n)
          ae[m][n] = __builtin_amdgcn_mfma_f32_16x16x32_bf16(a[m], b[n], ae[m][n], 0, 0, 0);
#pragma unroll
      for (int n = 0; n < 4; ++n) {
        const int c = wc * 64 + n * 16 + lr;
        b[n] = *reinterpret_cast<const bf16x8*>(sm + 49152 + c * 128 + (kc ^ ((c & 7) << 4)));
      }
#pragma unroll
      for (int m = 0; m < 4; ++m)
#pragma unroll
        for (int n = 0; n < 4; ++n)
          ax[m][n] = __builtin_amdgcn_mfma_f32_16x16x32_bf16(a[m], b[n], ax[m][n], 0, 0, 0);
    }
    __syncthreads();
  }

  // ---- epilogue (nontemporal output stores) ----
  float* const out2 = out + (size_t)BATCH * HD;
  const int n0 = bx * 128, m0 = by * 128;
#pragma unroll
  for (int n = 0; n < 4; ++n) {
    const int c = n0 + wc * 64 + n * 16 + lr;
    const float tb = th_b[c], eb = et_b[c];
#pragma unroll
    for (int m = 0; m < 4; ++m) {
#pragma unroll
      for (int v = 0; v < 4; ++v) {
        const int r = m0 + wr * 64 + m * 16 + lg * 4 + v;
        const float st = state[(size_t)r * HD + c];
        const float h = fsigmoid(at[m][n][v] + tb) * ftanh(st)
                      + fsigmoid(ae[m][n][v] + eb) * ftanh(ax[m][n][v]);
        __builtin_nontemporal_store(h, &out[(size_t)r * HD + c]);
        __builtin_nontemporal_store(h, &out2[(size_t)r * HD + c]);
      }
    }
  }
}

// ---------------- fallback if ws too small ----------------
__global__ __launch_bounds__(256, 2) void cfn_fallback(
    const float* __restrict__ inputs, const float* __restrict__ state,
    const float* __restrict__ th_u, const float* __restrict__ th_w,
    const float* __restrict__ th_b, const float* __restrict__ et_u,
    const float* __restrict__ et_w, const float* __restrict__ et_b,
    const float* __restrict__ wx_w, float* __restrict__ out) {
  __shared__ unsigned short sA[128 * 64];
  __shared__ unsigned short sB[128 * 64];
  char* const sAb = (char*)sA;
  char* const sBb = (char*)sB;
  const int tid = threadIdx.x;
  const int n0 = blockIdx.x * 128;
  const int m0 = blockIdx.y * 128;
  const int lane = tid & 63, wv = tid >> 6;
  const int wr = wv >> 1, wc = wv & 1;
  const int lr = lane & 15, lg = lane >> 4;
  const int a_kq = tid & 15, a_mb = tid >> 4;
  const int b_n = tid & 127, b_k8 = (tid >> 7) * 8;
  f32x4 acc[4][4], r2[4][4];
  auto zero_acc = [&]() {
#pragma unroll
    for (int m = 0; m < 4; ++m)
#pragma unroll
      for (int n = 0; n < 4; ++n) {
        acc[m][n][0] = 0.f; acc[m][n][1] = 0.f; acc[m][n][2] = 0.f; acc[m][n][3] = 0.f;
      }
  };
  auto gemm_seg = [&](const float* __restrict__ Ap, const float* __restrict__ Wp) {
    for (int k0 = 0; k0 < KD; k0 += 64) {
#pragma unroll
      for (int p = 0; p < 8; ++p) {
        const int m = p * 16 + a_mb;
        const float4 v = *reinterpret_cast<const float4*>(
            Ap + (size_t)(m0 + m) * KD + k0 + a_kq * 4);
        uint2 w;
        w.x = (unsigned)f2bf(v.x) | ((unsigned)f2bf(v.y) << 16);
        w.y = (unsigned)f2bf(v.z) | ((unsigned)f2bf(v.w) << 16);
        const int byte = m * 128 + ((a_kq * 8) ^ ((m & 7) << 4));
        *reinterpret_cast<uint2*>(sAb + byte) = w;
      }
#pragma unroll
      for (int p = 0; p < 4; ++p) {
        const int kb = p * 16 + b_k8;
        const float* bp = Wp + (size_t)(k0 + kb) * HD + n0 + b_n;
        uint4 w;
        w.x = (unsigned)f2bf(bp[0 * HD]) | ((unsigned)f2bf(bp[1 * HD]) << 16);
        w.y = (unsigned)f2bf(bp[2 * HD]) | ((unsigned)f2bf(bp[3 * HD]) << 16);
        w.z = (unsigned)f2bf(bp[4 * HD]) | ((unsigned)f2bf(bp[5 * HD]) << 16);
        w.w = (unsigned)f2bf(bp[6 * HD]) | ((unsigned)f2bf(bp[7 * HD]) << 16);
        const int byte = b_n * 128 + ((kb * 2) ^ ((b_n & 7) << 4));
        *reinterpret_cast<uint4*>(sBb + byte) = w;
      }
      __syncthreads();
#pragma unroll
      for (int kk = 0; kk < 2; ++kk) {
        bf16x8 af[4], bfr[4];
#pragma unroll
        for (int m = 0; m < 4; ++m) {
          const int r = wr * 64 + m * 16 + lr;
          af[m] = *reinterpret_cast<const bf16x8*>(sAb + r * 128 + ((kk * 64 + lg * 16) ^ ((r & 7) << 4)));
        }
#pragma unroll
        for (int n = 0; n < 4; ++n) {
          const int c = wc * 64 + n * 16 + lr;
          bfr[n] = *reinterpret_cast<const bf16x8*>(sBb + c * 128 + ((kk * 64 + lg * 16) ^ ((c & 7) << 4)));
        }
#pragma unroll
        for (int m = 0; m < 4; ++m)
#pragma unroll
          for (int n = 0; n < 4; ++n)
            acc[m][n] = __builtin_amdgcn_mfma_f32_16x16x32_bf16(af[m], bfr[n], acc[m][n], 0, 0, 0);
      }
      __syncthreads();
    }
  };
  zero_acc();
  gemm_seg(state, et_u);
  gemm_seg(inputs, et_w);
#pragma unroll
  for (int n = 0; n < 4; ++n) {
    const int c = n0 + wc * 64 + n * 16 + lr;
    const float eb = et_b[c];
#pragma unroll
    for (int m = 0; m < 4; ++m)
#pragma unroll
      for (int v = 0; v < 4; ++v) r2[m][n][v] = fsigmoid(acc[m][n][v] + eb);
  }
  zero_acc();
  gemm_seg(inputs, wx_w);
#pragma unroll
  for (int m = 0; m < 4; ++m)
#pragma unroll
    for (int n = 0; n < 4; ++n)
#pragma unroll
      for (int v = 0; v < 4; ++v) r2[m][n][v] *= ftanh(acc[m][n][v]);
  zero_acc();
  gemm_seg(state, th_u);
  gemm_seg(inputs, th_w);
  float* const out2 = out + (size_t)BATCH * HD;
#pragma unroll
  for (int n = 0; n < 4; ++n) {
    const int c = n0 + wc * 64 + n * 16 + lr;
    const float tb = th_b[c];
#pragma unroll
    for (int m = 0; m < 4; ++m)
#pragma unroll
      for (int v = 0; v < 4; ++v) {
        const int r = m0 + wr * 64 + m * 16 + lg * 4 + v;
        const float st = state[(size_t)r * HD + c];
        const float h = fsigmoid(acc[m][n][v] + tb) * ftanh(st) + r2[m][n][v];
        out[(size_t)r * HD + c] = h;
        out2[(size_t)r * HD + c] = h;
      }
  }
}

extern "C" void kernel_launch(void* const* d_in, const int* in_sizes, int n_in,
                              void* d_out, int out_size, void* d_ws, size_t ws_size,
                              hipStream_t stream) {
  const float* inputs = (const float*)d_in[0];
  const float* state  = (const float*)d_in[1];
  const float* th_u   = (const float*)d_in[2];
  const float* th_w   = (const float*)d_in[3];
  const float* th_b   = (const float*)d_in[4];
  const float* et_u   = (const float*)d_in[5];
  const float* et_w   = (const float*)d_in[6];
  const float* et_b   = (const float*)d_in[7];
  const float* wx_w   = (const float*)d_in[8];
  float* out = (float*)d_out;

  if (ws_size < WS_NEED) {
    dim3 grid(HD / 128, BATCH / 128);
    hipLaunchKernelGGL(cfn_fallback, grid, dim3(256), 0, stream,
                       inputs, state, th_u, th_w, th_b, et_u, et_w, et_b, wx_w, out);
    return;
  }

  char* ws = (char*)d_ws;
  hipLaunchKernelGGL(act_convert, dim3(8192), dim3(256), 0, stream, inputs, state, ws);
  hipLaunchKernelGGL(weight_convert, dim3(2560), dim3(256), 0, stream,
                     th_u, et_u, th_w, et_w, wx_w, ws);
  hipLaunchKernelGGL(cfn_main, dim3(512), dim3(256), 0, stream,
                     ws, state, th_b, et_b, out);
}